// Round 6
// baseline (256.054 us; speedup 1.0000x reference)
//
#include <hip/hip_runtime.h>
#include <math.h>

typedef float2 c32;

__device__ __forceinline__ c32 cadd(c32 a, c32 b){ return make_float2(a.x+b.x, a.y+b.y); }
__device__ __forceinline__ c32 csub(c32 a, c32 b){ return make_float2(a.x-b.x, a.y-b.y); }
__device__ __forceinline__ c32 cmul(c32 a, c32 b){ return make_float2(fmaf(a.x,b.x,-a.y*b.y), fmaf(a.x,b.y,a.y*b.x)); }
// a * conj(b)
__device__ __forceinline__ c32 cmulc(c32 a, c32 b){ return make_float2(fmaf(a.x,b.x, a.y*b.y), fmaf(a.y,b.x,-a.x*b.y)); }

__device__ __forceinline__ int dr4(int p){
  return ((p&3)<<6) | (((p>>2)&3)<<4) | (((p>>4)&3)<<2) | ((p>>6)&3);
}

// 16-pt radix-2 DIF, natural input, output reg r holds freq brev4(r).
template<int S>
__device__ __forceinline__ void dif16(c32 (&z)[16]){
  const float C1=0.92387953251128675613f, S1=0.38268343236508977173f, C2=0.70710678118654752440f;
  const float sg = (float)S;
  const c32 W[8] = { {1.f,0.f},{C1,sg*S1},{C2,sg*C2},{S1,sg*C1},{0.f,sg},{-S1,sg*C1},{-C2,sg*C2},{-C1,sg*S1} };
  #pragma unroll
  for(int j=0;j<8;j++){ c32 a=z[j], b=z[j+8]; z[j]=cadd(a,b); z[j+8]=cmul(csub(a,b), W[j]); }
  #pragma unroll
  for(int blk=0; blk<16; blk+=8){
    #pragma unroll
    for(int j=0;j<4;j++){ c32 a=z[blk+j], b=z[blk+j+4]; z[blk+j]=cadd(a,b); z[blk+j+4]=cmul(csub(a,b), W[2*j]); }
  }
  #pragma unroll
  for(int blk=0; blk<16; blk+=4){
    c32 a=z[blk], b=z[blk+2]; z[blk]=cadd(a,b); z[blk+2]=csub(a,b);
    c32 a1=z[blk+1], b1=z[blk+3]; c32 d=csub(a1,b1);
    z[blk+1]=cadd(a1,b1);
    z[blk+3]= (S<0)? make_float2(d.y,-d.x) : make_float2(-d.y,d.x);
  }
  #pragma unroll
  for(int blk=0; blk<16; blk+=2){ c32 a=z[blk], b=z[blk+1]; z[blk]=cadd(a,b); z[blk+1]=csub(a,b); }
}

// Same as dif16 but input z[8..15] are implicitly ZERO (only z[0..7] read).
template<int S>
__device__ __forceinline__ void dif16_pad(c32 (&z)[16]){
  const float C1=0.92387953251128675613f, S1=0.38268343236508977173f, C2=0.70710678118654752440f;
  const float sg = (float)S;
  const c32 W[8] = { {1.f,0.f},{C1,sg*S1},{C2,sg*C2},{S1,sg*C1},{0.f,sg},{-S1,sg*C1},{-C2,sg*C2},{-C1,sg*S1} };
  z[8]=z[0];
  #pragma unroll
  for(int j=1;j<8;j++) z[j+8]=cmul(z[j], W[j]);
  #pragma unroll
  for(int blk=0; blk<16; blk+=8){
    #pragma unroll
    for(int j=0;j<4;j++){ c32 a=z[blk+j], b=z[blk+j+4]; z[blk+j]=cadd(a,b); z[blk+j+4]=cmul(csub(a,b), W[2*j]); }
  }
  #pragma unroll
  for(int blk=0; blk<16; blk+=4){
    c32 a=z[blk], b=z[blk+2]; z[blk]=cadd(a,b); z[blk+2]=csub(a,b);
    c32 a1=z[blk+1], b1=z[blk+3]; c32 d=csub(a1,b1);
    z[blk+1]=cadd(a1,b1);
    z[blk+3]= (S<0)? make_float2(d.y,-d.x) : make_float2(-d.y,d.x);
  }
  #pragma unroll
  for(int blk=0; blk<16; blk+=2){ c32 a=z[blk], b=z[blk+1]; z[blk]=cadd(a,b); z[blk+1]=csub(a,b); }
}

// Same as dif16 but only EVEN output regs are produced (odd regs garbage) — for cropped stores.
template<int S>
__device__ __forceinline__ void dif16_crop(c32 (&z)[16]){
  const float C1=0.92387953251128675613f, S1=0.38268343236508977173f, C2=0.70710678118654752440f;
  const float sg = (float)S;
  const c32 W[8] = { {1.f,0.f},{C1,sg*S1},{C2,sg*C2},{S1,sg*C1},{0.f,sg},{-S1,sg*C1},{-C2,sg*C2},{-C1,sg*S1} };
  #pragma unroll
  for(int j=0;j<8;j++){ c32 a=z[j], b=z[j+8]; z[j]=cadd(a,b); z[j+8]=cmul(csub(a,b), W[j]); }
  #pragma unroll
  for(int blk=0; blk<16; blk+=8){
    #pragma unroll
    for(int j=0;j<4;j++){ c32 a=z[blk+j], b=z[blk+j+4]; z[blk+j]=cadd(a,b); z[blk+j+4]=cmul(csub(a,b), W[2*j]); }
  }
  #pragma unroll
  for(int blk=0; blk<16; blk+=4){
    c32 a=z[blk], b=z[blk+2]; z[blk]=cadd(a,b); z[blk+2]=csub(a,b);
    c32 a1=z[blk+1], b1=z[blk+3]; c32 d=csub(a1,b1);
    z[blk+1]=cadd(a1,b1);
    z[blk+3]= (S<0)? make_float2(d.y,-d.x) : make_float2(-d.y,d.x);
  }
  #pragma unroll
  for(int blk=0; blk<16; blk+=2){ z[blk]=cadd(z[blk], z[blk+1]); }   // even outputs only
}

// 16-pt radix-2 DIT, input reg r holds X[brev4(r)], natural output, W=e^{+2pi i/16}.
__device__ __forceinline__ void dit16(c32 (&z)[16]){
  const float C1=0.92387953251128675613f, S1=0.38268343236508977173f, C2=0.70710678118654752440f;
  const c32 Wc[8] = { {1.f,0.f},{C1,S1},{C2,C2},{S1,C1},{0.f,1.f},{-S1,C1},{-C2,C2},{-C1,S1} };
  #pragma unroll
  for(int p=0;p<16;p+=2){ c32 a=z[p], b=z[p+1]; z[p]=cadd(a,b); z[p+1]=csub(a,b); }
  #pragma unroll
  for(int g=0;g<16;g+=4){
    c32 t=z[g+2]; z[g+2]=csub(z[g],t); z[g]=cadd(z[g],t);
    c32 u=z[g+3]; c32 t1=make_float2(-u.y,u.x); z[g+3]=csub(z[g+1],t1); z[g+1]=cadd(z[g+1],t1);
  }
  #pragma unroll
  for(int g=0;g<16;g+=8){
    #pragma unroll
    for(int j=0;j<4;j++){ c32 t=cmul(z[g+4+j], Wc[2*j]); z[g+4+j]=csub(z[g+j],t); z[g+j]=cadd(z[g+j],t); }
  }
  #pragma unroll
  for(int j=0;j<8;j++){ c32 t=cmul(z[8+j], Wc[j]); z[8+j]=csub(z[j],t); z[j]=cadd(z[j],t); }
}

// ---------------- K0: build A (256x96 complex, rows stored digit-reversed) + twiddle table ----------------
__launch_bounds__(256)
__global__ void k_setup(const float* __restrict__ mtx, const float* __restrict__ wave,
                        const int* __restrict__ tbes, c32* __restrict__ A, c32* __restrict__ T,
                        int K, int P){
  __shared__ double2 w256[256];
  __shared__ double gre[128];
  __shared__ double gim[128];
  int tid=threadIdx.x; int v=blockIdx.x;
  double ang = -6.2831853071795864769252867665590 * (double)tid / 256.0;
  w256[tid]=make_double2(cos(ang), sin(ang));
  if(v==0) T[tid]=make_float2((float)w256[tid].x,(float)w256[tid].y);
  __syncthreads();
  if(tid<128){
    int tbe=tbes[0];
    double sr=0.0, si=0.0;
    for(int t=0;t<128;t++){
      int jj = v + tbe + P - t;
      if(jj>=0 && jj<K){
        double mv=(double)mtx[tid*128+t];
        sr += mv*(double)wave[jj];
        si += mv*(double)wave[K+jj];
      }
    }
    gre[tid]=sr; gim[tid]=si;
  }
  __syncthreads();
  double ar=0.0, ai=0.0;
  int k=tid;
  for(int m=0;m<128;m++){
    double2 f=w256[(k*m)&255];
    ar += f.x*gre[m] - f.y*gim[m];
    ai += f.x*gim[m] + f.y*gre[m];
  }
  A[(long)dr4(k)*96 + v] = make_float2((float)ar,(float)ai);
}

// ---------------- K1: fused pad+conv+mtx+zeropad+FFT_z  (SPEC[d][k][h][w] = sum_v A[k,v]*feat[d,v,h,w]) ----
__launch_bounds__(256)
__global__ void k_front(const float* __restrict__ feat, const c32* __restrict__ A, c32* __restrict__ buf){
  __shared__ __align__(16) float Xs[48*128];
  __shared__ __align__(16) c32 As[64*48];
  int tid=threadIdx.x; int b=blockIdx.x;
  int d=b>>9, h=(b>>2)&127, kb=(b&3)*64;
  c32 acc[8][4];
  #pragma unroll
  for(int i=0;i<8;i++){
    #pragma unroll
    for(int j=0;j<4;j++) acc[i][j]=make_float2(0.f,0.f);
  }
  int kg=tid>>5, wg=tid&31;
  for(int vc=0; vc<2; vc++){
    #pragma unroll
    for(int i=0;i<6;i++){
      int idx=tid+i*256;
      int v=idx>>5, w4=idx&31;
      *(float4*)&Xs[v*128 + w4*4] = *(const float4*)&feat[(((long)d*96 + vc*48+v)*128 + h)*128 + w4*4];
    }
    #pragma unroll
    for(int i=0;i<6;i++){
      int idx=tid+i*256;
      int kk=idx/24, rem=idx-kk*24;
      *(float4*)&As[kk*48 + rem*2] = *(const float4*)&A[(long)(kb+kk)*96 + vc*48 + rem*2];
    }
    __syncthreads();
    #pragma unroll 4
    for(int vv=0; vv<48; vv++){
      float4 xv = *(const float4*)&Xs[vv*128 + wg*4];
      #pragma unroll
      for(int i=0;i<8;i++){
        c32 a = As[(kg*8+i)*48 + vv];
        acc[i][0].x = fmaf(a.x, xv.x, acc[i][0].x); acc[i][0].y = fmaf(a.y, xv.x, acc[i][0].y);
        acc[i][1].x = fmaf(a.x, xv.y, acc[i][1].x); acc[i][1].y = fmaf(a.y, xv.y, acc[i][1].y);
        acc[i][2].x = fmaf(a.x, xv.z, acc[i][2].x); acc[i][2].y = fmaf(a.y, xv.z, acc[i][2].y);
        acc[i][3].x = fmaf(a.x, xv.w, acc[i][3].x); acc[i][3].y = fmaf(a.y, xv.w, acc[i][3].y);
      }
    }
    __syncthreads();
  }
  #pragma unroll
  for(int i=0;i<8;i++){
    int k=kb+kg*8+i;
    long o = (((long)d*256 + k)*256 + h)*128 + wg*4;
    *(float4*)&buf[o]   = make_float4(acc[i][0].x,acc[i][0].y,acc[i][1].x,acc[i][1].y);
    *(float4*)&buf[o+2] = make_float4(acc[i][2].x,acc[i][2].y,acc[i][3].x,acc[i][3].y);
  }
}

// ---------------- K2: forward 256-pt radix-4 DIF along q (rows 128..255 are zero; folded into load) -------
__launch_bounds__(256)
__global__ void k_ffty(c32* __restrict__ buf, const c32* __restrict__ T){
  __shared__ c32 tile[256*17];
  __shared__ c32 Ts[256];
  int tid=threadIdx.x;
  Ts[tid]=T[tid];
  int b=blockIdx.x;
  int d=b>>11, k=(b>>3)&255, w0=(b&7)*16;
  long base = (((long)d*256 + k)*256)*128 + w0;
  __syncthreads();
  #pragma unroll
  for(int it=0; it<4; it++){
    int idx = tid + it*256; int w = idx&15, j = idx>>4;
    c32 x0 = buf[base + (long)j*128 + w];
    c32 x1 = buf[base + (long)(j+64)*128 + w];
    tile[j*17+w] = cadd(x0,x1);
    c32 y1 = make_float2(x0.x + x1.y, x0.y - x1.x);   // x0 - i*x1
    c32 y2 = csub(x0,x1);
    c32 y3 = make_float2(x0.x - x1.y, x0.y + x1.x);   // x0 + i*x1
    tile[(j+64)*17+w]  = cmul(y1, Ts[j]);
    tile[(j+128)*17+w] = cmul(y2, Ts[(2*j)&255]);
    tile[(j+192)*17+w] = cmul(y3, Ts[(3*j)&255]);
  }
  __syncthreads();
  #pragma unroll
  for(int s=1;s<4;s++){
    int quarter = 64 >> (2*s);
    int m4 = quarter<<2;
    int sh = 2*s;
    #pragma unroll
    for(int it=0;it<4;it++){
      int idx=tid+it*256; int w=idx&15, bf=idx>>4;
      int g = bf/quarter, j = bf - g*quarter;
      int p0 = g*m4 + j;
      c32 x0=tile[p0*17+w], x1=tile[(p0+quarter)*17+w], x2=tile[(p0+2*quarter)*17+w], x3=tile[(p0+3*quarter)*17+w];
      c32 t0=cadd(x0,x2), t1=csub(x0,x2), t2=cadd(x1,x3), t3=csub(x1,x3);
      c32 y0=cadd(t0,t2);
      c32 y2=csub(t0,t2);
      c32 y1=make_float2(t1.x + t3.y, t1.y - t3.x);   // t1 - i*t3
      c32 y3=make_float2(t1.x - t3.y, t1.y + t3.x);   // t1 + i*t3
      tile[p0*17+w]=y0;
      tile[(p0+quarter)*17+w]  =cmul(y1, Ts[(j<<sh)&255]);
      tile[(p0+2*quarter)*17+w]=cmul(y2, Ts[((2*j)<<sh)&255]);
      tile[(p0+3*quarter)*17+w]=cmul(y3, Ts[((3*j)<<sh)&255]);
    }
    __syncthreads();
  }
  #pragma unroll
  for(int it=0;it<16;it++){
    int idx=tid+it*256; int w=idx&15, p=idx>>4;
    buf[base + (long)p*128 + w] = tile[p*17+w];
  }
}

// ---------------- K34: fused x-FFT * invpsf * x-IFFT per line; wave-synchronous; half-width transposes ----
// Per-line LDS = 16 rows x 8 cols (stride 9), line stride 148 c32 -> 20.9 KB/block -> 7 blocks/CU.
__launch_bounds__(256)
__global__ void k_fftx(c32* __restrict__ buf, const float* __restrict__ pre,
                       const float* __restrict__ pim, const c32* __restrict__ T){
  __shared__ c32 tile[16*148];
  __shared__ c32 Ts[256];
  const int BR[16]={0,8,4,12,2,10,6,14,1,9,5,13,3,11,7,15};
  int tid=threadIdx.x;
  Ts[tid]=T[tid];
  int lane = tid & 63;
  int L = ((tid>>6)<<2) + (lane>>4);   // 0..15 : line within block
  int n1 = lane & 15;
  int k = blockIdx.x >> 5;
  int q = ((blockIdx.x & 31)<<3) + (L & 7);
  int d = L >> 3;
  long lbase = (((long)d*256 + k)*256 + q)*128;
  long prow = (((long)dr4(k))*256 + dr4(q))*256;
  c32* tl = &tile[L*148];
  bool lo = (n1 < 8);
  int wc = n1 & 7;
  const float* pb_re = pre + prow + n1;
  const float* pb_im = pim + prow + n1;
  c32 h[16];
  #pragma unroll
  for(int r=0;r<16;r++){ h[r].x = pb_re[16*BR[r]]; h[r].y = pb_im[16*BR[r]]; }
  c32 z[16];
  #pragma unroll
  for(int r=0;r<8;r++) z[r] = buf[lbase + n1 + 16*r];
  __syncthreads();                       // Ts visible; the ONLY block barrier
  // forward: FFT16 over n2 (upper half zero)
  dif16_pad<-1>(z);
  #pragma unroll
  for(int r=1;r<16;r++) z[r] = cmul(z[r], Ts[(n1*BR[r])&255]);
  // ---- transpose A: dest row BR[r]; column-half buffer used twice (wave-private region) ----
  {
    c32 t[8];
    if(lo){
      #pragma unroll
      for(int r=0;r<16;r++) tl[BR[r]*9 + wc] = z[r];
    }
    __builtin_amdgcn_wave_barrier();
    #pragma unroll
    for(int c=0;c<8;c++) t[c] = tl[n1*9 + c];          // cols 0..7
    __builtin_amdgcn_wave_barrier();
    if(!lo){
      #pragma unroll
      for(int r=0;r<16;r++) tl[BR[r]*9 + wc] = z[r];
    }
    __builtin_amdgcn_wave_barrier();
    #pragma unroll
    for(int c=0;c<8;c++) z[8+c] = tl[n1*9 + c];        // cols 8..15
    #pragma unroll
    for(int c=0;c<8;c++) z[c] = t[c];
  }
  // forward: FFT16 over n1 (lane now plays role k2)
  dif16<-1>(z);
  // pointwise multiply by invpsf (natural kx = n1 + 16*BR[r])
  #pragma unroll
  for(int r=0;r<16;r++) z[r] = cmul(z[r], h[r]);
  // inverse: IFFT16 over k1
  dit16(z);
  #pragma unroll
  for(int r=1;r<16;r++) z[r] = cmulc(z[r], Ts[(r*n1)&255]);
  // ---- transpose B: dest row r (natural) ----
  {
    c32 t[8];
    __builtin_amdgcn_wave_barrier();
    if(lo){
      #pragma unroll
      for(int r=0;r<16;r++) tl[r*9 + wc] = z[r];
    }
    __builtin_amdgcn_wave_barrier();
    #pragma unroll
    for(int c=0;c<8;c++) t[c] = tl[n1*9 + c];
    __builtin_amdgcn_wave_barrier();
    if(!lo){
      #pragma unroll
      for(int r=0;r<16;r++) tl[r*9 + wc] = z[r];
    }
    __builtin_amdgcn_wave_barrier();
    #pragma unroll
    for(int c=0;c<8;c++) z[8+c] = tl[n1*9 + c];
    #pragma unroll
    for(int c=0;c<8;c++) z[c] = t[c];
  }
  // inverse: IFFT16 over k2; only n = n1+16*n2 < 128 kept (even regs)
  dif16_crop<1>(z);
  const float s = 1.f/256.f;
  #pragma unroll
  for(int r=0;r<16;r+=2){
    int n2 = BR[r];
    buf[lbase + n1 + 16*n2] = make_float2(z[r].x*s, z[r].y*s);
  }
}

// ---------------- K5: inverse 256-pt radix-4 DIT along q, crop q<128, in-place -----------------------------
__launch_bounds__(256)
__global__ void k_iffty(c32* __restrict__ buf, const c32* __restrict__ T){
  __shared__ c32 tile[256*17];
  __shared__ c32 Ts[256];
  int tid=threadIdx.x;
  Ts[tid]=T[tid];
  int b=blockIdx.x;
  int d=b>>11, k=(b>>3)&255, x0=(b&7)*16;
  long base = (((long)d*256 + k)*256)*128 + x0;
  __syncthreads();
  #pragma unroll
  for(int it=0;it<16;it++){
    int idx=tid+it*256; int w=idx&15, p=idx>>4;
    tile[p*17+w]=buf[base + (long)p*128 + w];
  }
  __syncthreads();
  #pragma unroll
  for(int s=0;s<3;s++){
    int quarter = 1<<(2*s);
    int m4 = quarter<<2;
    int sh = 2*(3-s);
    #pragma unroll
    for(int it=0;it<4;it++){
      int idx=tid+it*256; int w=idx&15, bf=idx>>4;
      int g=bf/quarter, j=bf-g*quarter;
      int p0=g*m4+j;
      c32 t0=tile[p0*17+w];
      c32 t1=cmulc(tile[(p0+quarter)*17+w],   Ts[(j<<sh)&255]);
      c32 t2=cmulc(tile[(p0+2*quarter)*17+w], Ts[((2*j)<<sh)&255]);
      c32 t3=cmulc(tile[(p0+3*quarter)*17+w], Ts[((3*j)<<sh)&255]);
      c32 y0 = make_float2(t0.x+t1.x+t2.x+t3.x, t0.y+t1.y+t2.y+t3.y);
      c32 y1 = make_float2(t0.x - t1.y - t2.x + t3.y, t0.y + t1.x - t2.y - t3.x);
      c32 y2 = make_float2(t0.x - t1.x + t2.x - t3.x, t0.y - t1.y + t2.y - t3.y);
      c32 y3 = make_float2(t0.x + t1.y - t2.x - t3.y, t0.y - t1.x - t2.y + t3.x);
      tile[p0*17+w]=y0; tile[(p0+quarter)*17+w]=y1; tile[(p0+2*quarter)*17+w]=y2; tile[(p0+3*quarter)*17+w]=y3;
    }
    __syncthreads();
  }
  const float sc = 1.f/256.f;
  #pragma unroll
  for(int it=0;it<4;it++){
    int idx=tid+it*256; int w=idx&15, j=idx>>4;
    c32 t0=tile[j*17+w];
    c32 t1=cmulc(tile[(j+64)*17+w],  Ts[j]);
    c32 t2=cmulc(tile[(j+128)*17+w], Ts[(2*j)&255]);
    c32 t3=cmulc(tile[(j+192)*17+w], Ts[(3*j)&255]);
    c32 y0 = make_float2((t0.x+t1.x+t2.x+t3.x)*sc, (t0.y+t1.y+t2.y+t3.y)*sc);
    c32 y1 = make_float2((t0.x - t1.y - t2.x + t3.y)*sc, (t0.y + t1.x - t2.y - t3.x)*sc);
    buf[base + (long)j*128 + w] = y0;
    buf[base + (long)(j+64)*128 + w] = y1;
  }
}

// ---------------- K6: inverse 256-pt DIT along k (z), crop z<128, magnitude, fused mtxi matmul -> out -----
__launch_bounds__(256)
__global__ void k_back(c32* __restrict__ buf, const float* __restrict__ mtxi,
                       const c32* __restrict__ T, float* __restrict__ out){
  __shared__ c32 tile[256*17];     // FFT tile; reused as mtxi chunk [128 t][68] floats in phase 2
  __shared__ float magl[128*16];   // mag[t][x] for this block's 16 x
  __shared__ c32 Ts[256];
  int tid=threadIdx.x;
  Ts[tid]=T[tid];
  int b=blockIdx.x;
  int d=b>>10, y=(b>>3)&127, x0=(b&7)*16;
  __syncthreads();
  #pragma unroll
  for(int it=0;it<16;it++){
    int idx=tid+it*256; int w=idx&15, p=idx>>4;
    tile[p*17+w]=buf[(((long)d*256 + p)*256 + y)*128 + x0 + w];
  }
  __syncthreads();
  #pragma unroll
  for(int s=0;s<3;s++){
    int quarter = 1<<(2*s);
    int m4 = quarter<<2;
    int sh = 2*(3-s);
    #pragma unroll
    for(int it=0;it<4;it++){
      int idx=tid+it*256; int w=idx&15, bf=idx>>4;
      int g=bf/quarter, j=bf-g*quarter;
      int p0=g*m4+j;
      c32 t0=tile[p0*17+w];
      c32 t1=cmulc(tile[(p0+quarter)*17+w],   Ts[(j<<sh)&255]);
      c32 t2=cmulc(tile[(p0+2*quarter)*17+w], Ts[((2*j)<<sh)&255]);
      c32 t3=cmulc(tile[(p0+3*quarter)*17+w], Ts[((3*j)<<sh)&255]);
      c32 y0 = make_float2(t0.x+t1.x+t2.x+t3.x, t0.y+t1.y+t2.y+t3.y);
      c32 y1 = make_float2(t0.x - t1.y - t2.x + t3.y, t0.y + t1.x - t2.y - t3.x);
      c32 y2 = make_float2(t0.x - t1.x + t2.x - t3.x, t0.y - t1.y + t2.y - t3.y);
      c32 y3 = make_float2(t0.x + t1.y - t2.x - t3.y, t0.y - t1.x - t2.y + t3.x);
      tile[p0*17+w]=y0; tile[(p0+quarter)*17+w]=y1; tile[(p0+2*quarter)*17+w]=y2; tile[(p0+3*quarter)*17+w]=y3;
    }
    __syncthreads();
  }
  const float sc = 1.f/256.f;
  #pragma unroll
  for(int it=0;it<4;it++){
    int idx=tid+it*256; int w=idx&15, j=idx>>4;
    c32 t0=tile[j*17+w];
    c32 t1=cmulc(tile[(j+64)*17+w],  Ts[j]);
    c32 t2=cmulc(tile[(j+128)*17+w], Ts[(2*j)&255]);
    c32 t3=cmulc(tile[(j+192)*17+w], Ts[(3*j)&255]);
    float y0r = t0.x+t1.x+t2.x+t3.x, y0i = t0.y+t1.y+t2.y+t3.y;
    float y1r = t0.x - t1.y - t2.x + t3.y, y1i = t0.y + t1.x - t2.y - t3.x;
    magl[j*16 + w]      = sqrtf(y0r*y0r + y0i*y0i) * sc;
    magl[(j+64)*16 + w] = sqrtf(y1r*y1r + y1i*y1i) * sc;
  }
  __syncthreads();
  // ---- phase 2: out[d, m, y, x0+xg*4..+3] = sum_t mtxi[m,t] * magl[t][x]
  float* mt = (float*)tile;        // [128 t][68] chunk of 64 m (33 KB <= 34.8 KB)
  int xg = tid&3, mg = tid>>2;     // 64 mg x 4 xg
  #pragma unroll
  for(int c=0;c<2;c++){
    #pragma unroll
    for(int it=0;it<32;it++){
      int idx=tid+it*256; int t=idx&127, mm=idx>>7;
      mt[t*68+mm] = mtxi[(c*64+mm)*128 + t];
    }
    __syncthreads();
    float4 a = make_float4(0.f,0.f,0.f,0.f);
    #pragma unroll 4
    for(int t=0;t<128;t++){
      float mv = mt[t*68 + mg];
      float4 g = *(const float4*)&magl[t*16 + xg*4];
      a.x = fmaf(mv, g.x, a.x); a.y = fmaf(mv, g.y, a.y);
      a.z = fmaf(mv, g.z, a.z); a.w = fmaf(mv, g.w, a.w);
    }
    int m_ = c*64 + mg;
    *(float4*)&out[(((long)d*128 + m_)*128 + y)*128 + x0 + xg*4] = a;
    __syncthreads();
  }
}

extern "C" void kernel_launch(void* const* d_in, const int* in_sizes, int n_in,
                              void* d_out, int out_size, void* d_ws, size_t ws_size,
                              hipStream_t stream) {
  const float* feat=(const float*)d_in[0];
  const float* wave=(const float*)d_in[1];
  const float* mtx =(const float*)d_in[2];
  const float* mtxi=(const float*)d_in[3];
  const float* pre =(const float*)d_in[4];
  const float* pim =(const float*)d_in[5];
  const int*   tbes=(const int*)d_in[6];
  float* out=(float*)d_out;
  char* ws=(char*)d_ws;
  c32* A   = (c32*)ws;               // 256*96*8      = 196608 B
  c32* T   = (c32*)(ws + 196608);    // 256*8         = 2048 B
  c32* buf = (c32*)(ws + 262144);    // 2*256*256*128*8 = 134217728 B

  int K = in_sizes[1] / 2;           // wave_2x1xk -> k taps
  int P = (K & 1) ? (K/2) : (K/2 - 1);

  hipLaunchKernelGGL(k_setup, dim3(96),   dim3(256), 0, stream, mtx, wave, tbes, A, T, K, P);
  hipLaunchKernelGGL(k_front, dim3(1024), dim3(256), 0, stream, feat, A, buf);
  hipLaunchKernelGGL(k_ffty,  dim3(4096), dim3(256), 0, stream, buf, T);
  hipLaunchKernelGGL(k_fftx,  dim3(8192), dim3(256), 0, stream, buf, pre, pim, T);
  hipLaunchKernelGGL(k_iffty, dim3(4096), dim3(256), 0, stream, buf, T);
  hipLaunchKernelGGL(k_back,  dim3(2048), dim3(256), 0, stream, buf, mtxi, T, out);
}

// Round 8
// 247.793 us; speedup vs baseline: 1.0333x; 1.0333x over previous
//
#include <hip/hip_runtime.h>
#include <math.h>

typedef float2 c32;

__device__ __forceinline__ c32 cadd(c32 a, c32 b){ return make_float2(a.x+b.x, a.y+b.y); }
__device__ __forceinline__ c32 csub(c32 a, c32 b){ return make_float2(a.x-b.x, a.y-b.y); }
__device__ __forceinline__ c32 cmul(c32 a, c32 b){ return make_float2(fmaf(a.x,b.x,-a.y*b.y), fmaf(a.x,b.y,a.y*b.x)); }
// a * conj(b)
__device__ __forceinline__ c32 cmulc(c32 a, c32 b){ return make_float2(fmaf(a.x,b.x, a.y*b.y), fmaf(a.y,b.x,-a.x*b.y)); }

__device__ __forceinline__ c32 ntload(const c32* p){
  double v = __builtin_nontemporal_load(reinterpret_cast<const double*>(p));
  union { double d; float f[2]; } u; u.d = v;
  return make_float2(u.f[0], u.f[1]);
}
__device__ __forceinline__ void ntstore(c32* p, c32 v){
  union { double d; float f[2]; } u; u.f[0]=v.x; u.f[1]=v.y;
  __builtin_nontemporal_store(u.d, reinterpret_cast<double*>(p));
}

__device__ __forceinline__ int dr4(int p){
  return ((p&3)<<6) | (((p>>2)&3)<<4) | (((p>>4)&3)<<2) | ((p>>6)&3);
}

// 16-pt radix-2 DIF, natural input, output reg r holds freq brev4(r).
template<int S>
__device__ __forceinline__ void dif16(c32 (&z)[16]){
  const float C1=0.92387953251128675613f, S1=0.38268343236508977173f, C2=0.70710678118654752440f;
  const float sg = (float)S;
  const c32 W[8] = { {1.f,0.f},{C1,sg*S1},{C2,sg*C2},{S1,sg*C1},{0.f,sg},{-S1,sg*C1},{-C2,sg*C2},{-C1,sg*S1} };
  #pragma unroll
  for(int j=0;j<8;j++){ c32 a=z[j], b=z[j+8]; z[j]=cadd(a,b); z[j+8]=cmul(csub(a,b), W[j]); }
  #pragma unroll
  for(int blk=0; blk<16; blk+=8){
    #pragma unroll
    for(int j=0;j<4;j++){ c32 a=z[blk+j], b=z[blk+j+4]; z[blk+j]=cadd(a,b); z[blk+j+4]=cmul(csub(a,b), W[2*j]); }
  }
  #pragma unroll
  for(int blk=0; blk<16; blk+=4){
    c32 a=z[blk], b=z[blk+2]; z[blk]=cadd(a,b); z[blk+2]=csub(a,b);
    c32 a1=z[blk+1], b1=z[blk+3]; c32 d=csub(a1,b1);
    z[blk+1]=cadd(a1,b1);
    z[blk+3]= (S<0)? make_float2(d.y,-d.x) : make_float2(-d.y,d.x);
  }
  #pragma unroll
  for(int blk=0; blk<16; blk+=2){ c32 a=z[blk], b=z[blk+1]; z[blk]=cadd(a,b); z[blk+1]=csub(a,b); }
}

// Same as dif16 but input z[8..15] are implicitly ZERO (only z[0..7] read).
template<int S>
__device__ __forceinline__ void dif16_pad(c32 (&z)[16]){
  const float C1=0.92387953251128675613f, S1=0.38268343236508977173f, C2=0.70710678118654752440f;
  const float sg = (float)S;
  const c32 W[8] = { {1.f,0.f},{C1,sg*S1},{C2,sg*C2},{S1,sg*C1},{0.f,sg},{-S1,sg*C1},{-C2,sg*C2},{-C1,sg*S1} };
  z[8]=z[0];
  #pragma unroll
  for(int j=1;j<8;j++) z[j+8]=cmul(z[j], W[j]);
  #pragma unroll
  for(int blk=0; blk<16; blk+=8){
    #pragma unroll
    for(int j=0;j<4;j++){ c32 a=z[blk+j], b=z[blk+j+4]; z[blk+j]=cadd(a,b); z[blk+j+4]=cmul(csub(a,b), W[2*j]); }
  }
  #pragma unroll
  for(int blk=0; blk<16; blk+=4){
    c32 a=z[blk], b=z[blk+2]; z[blk]=cadd(a,b); z[blk+2]=csub(a,b);
    c32 a1=z[blk+1], b1=z[blk+3]; c32 d=csub(a1,b1);
    z[blk+1]=cadd(a1,b1);
    z[blk+3]= (S<0)? make_float2(d.y,-d.x) : make_float2(-d.y,d.x);
  }
  #pragma unroll
  for(int blk=0; blk<16; blk+=2){ c32 a=z[blk], b=z[blk+1]; z[blk]=cadd(a,b); z[blk+1]=csub(a,b); }
}

// Same as dif16 but only EVEN output regs are produced (odd regs garbage) — for cropped stores.
template<int S>
__device__ __forceinline__ void dif16_crop(c32 (&z)[16]){
  const float C1=0.92387953251128675613f, S1=0.38268343236508977173f, C2=0.70710678118654752440f;
  const float sg = (float)S;
  const c32 W[8] = { {1.f,0.f},{C1,sg*S1},{C2,sg*C2},{S1,sg*C1},{0.f,sg},{-S1,sg*C1},{-C2,sg*C2},{-C1,sg*S1} };
  #pragma unroll
  for(int j=0;j<8;j++){ c32 a=z[j], b=z[j+8]; z[j]=cadd(a,b); z[j+8]=cmul(csub(a,b), W[j]); }
  #pragma unroll
  for(int blk=0; blk<16; blk+=8){
    #pragma unroll
    for(int j=0;j<4;j++){ c32 a=z[blk+j], b=z[blk+j+4]; z[blk+j]=cadd(a,b); z[blk+j+4]=cmul(csub(a,b), W[2*j]); }
  }
  #pragma unroll
  for(int blk=0; blk<16; blk+=4){
    c32 a=z[blk], b=z[blk+2]; z[blk]=cadd(a,b); z[blk+2]=csub(a,b);
    c32 a1=z[blk+1], b1=z[blk+3]; c32 d=csub(a1,b1);
    z[blk+1]=cadd(a1,b1);
    z[blk+3]= (S<0)? make_float2(d.y,-d.x) : make_float2(-d.y,d.x);
  }
  #pragma unroll
  for(int blk=0; blk<16; blk+=2){ z[blk]=cadd(z[blk], z[blk+1]); }   // even outputs only
}

// 16-pt radix-2 DIT, input reg r holds X[brev4(r)], natural output, W=e^{+2pi i/16}.
__device__ __forceinline__ void dit16(c32 (&z)[16]){
  const float C1=0.92387953251128675613f, S1=0.38268343236508977173f, C2=0.70710678118654752440f;
  const c32 Wc[8] = { {1.f,0.f},{C1,S1},{C2,C2},{S1,C1},{0.f,1.f},{-S1,C1},{-C2,C2},{-C1,S1} };
  #pragma unroll
  for(int p=0;p<16;p+=2){ c32 a=z[p], b=z[p+1]; z[p]=cadd(a,b); z[p+1]=csub(a,b); }
  #pragma unroll
  for(int g=0;g<16;g+=4){
    c32 t=z[g+2]; z[g+2]=csub(z[g],t); z[g]=cadd(z[g],t);
    c32 u=z[g+3]; c32 t1=make_float2(-u.y,u.x); z[g+3]=csub(z[g+1],t1); z[g+1]=cadd(z[g+1],t1);
  }
  #pragma unroll
  for(int g=0;g<16;g+=8){
    #pragma unroll
    for(int j=0;j<4;j++){ c32 t=cmul(z[g+4+j], Wc[2*j]); z[g+4+j]=csub(z[g+j],t); z[g+j]=cadd(z[g+j],t); }
  }
  #pragma unroll
  for(int j=0;j<8;j++){ c32 t=cmul(z[8+j], Wc[j]); z[8+j]=csub(z[j],t); z[j]=cadd(z[j],t); }
}

// ---------------- K0: build A (256x96 complex, rows stored digit-reversed) + twiddle table ----------------
__launch_bounds__(256)
__global__ void k_setup(const float* __restrict__ mtx, const float* __restrict__ wave,
                        const int* __restrict__ tbes, c32* __restrict__ A, c32* __restrict__ T,
                        int K, int P){
  __shared__ double2 w256[256];
  __shared__ double gre[128];
  __shared__ double gim[128];
  int tid=threadIdx.x; int v=blockIdx.x;
  double ang = -6.2831853071795864769252867665590 * (double)tid / 256.0;
  w256[tid]=make_double2(cos(ang), sin(ang));
  if(v==0) T[tid]=make_float2((float)w256[tid].x,(float)w256[tid].y);
  __syncthreads();
  if(tid<128){
    int tbe=tbes[0];
    double sr=0.0, si=0.0;
    for(int t=0;t<128;t++){
      int jj = v + tbe + P - t;
      if(jj>=0 && jj<K){
        double mv=(double)mtx[tid*128+t];
        sr += mv*(double)wave[jj];
        si += mv*(double)wave[K+jj];
      }
    }
    gre[tid]=sr; gim[tid]=si;
  }
  __syncthreads();
  double ar=0.0, ai=0.0;
  int k=tid;
  for(int m=0;m<128;m++){
    double2 f=w256[(k*m)&255];
    ar += f.x*gre[m] - f.y*gim[m];
    ai += f.x*gim[m] + f.y*gre[m];
  }
  A[(long)dr4(k)*96 + v] = make_float2((float)ar,(float)ai);
}

// ---------------- K1: fused pad+conv+mtx+zeropad+FFT_z  (SPEC[d][k][h][w] = sum_v A[k,v]*feat[d,v,h,w]) ----
__launch_bounds__(256)
__global__ void k_front(const float* __restrict__ feat, const c32* __restrict__ A, c32* __restrict__ buf){
  __shared__ __align__(16) float Xs[48*128];
  __shared__ __align__(16) c32 As[64*48];
  int tid=threadIdx.x; int b=blockIdx.x;
  int d=b>>9, h=(b>>2)&127, kb=(b&3)*64;
  c32 acc[8][4];
  #pragma unroll
  for(int i=0;i<8;i++){
    #pragma unroll
    for(int j=0;j<4;j++) acc[i][j]=make_float2(0.f,0.f);
  }
  int kg=tid>>5, wg=tid&31;
  for(int vc=0; vc<2; vc++){
    #pragma unroll
    for(int i=0;i<6;i++){
      int idx=tid+i*256;
      int v=idx>>5, w4=idx&31;
      *(float4*)&Xs[v*128 + w4*4] = *(const float4*)&feat[(((long)d*96 + vc*48+v)*128 + h)*128 + w4*4];
    }
    #pragma unroll
    for(int i=0;i<6;i++){
      int idx=tid+i*256;
      int kk=idx/24, rem=idx-kk*24;
      *(float4*)&As[kk*48 + rem*2] = *(const float4*)&A[(long)(kb+kk)*96 + vc*48 + rem*2];
    }
    __syncthreads();
    #pragma unroll 4
    for(int vv=0; vv<48; vv++){
      float4 xv = *(const float4*)&Xs[vv*128 + wg*4];
      #pragma unroll
      for(int i=0;i<8;i++){
        c32 a = As[(kg*8+i)*48 + vv];
        acc[i][0].x = fmaf(a.x, xv.x, acc[i][0].x); acc[i][0].y = fmaf(a.y, xv.x, acc[i][0].y);
        acc[i][1].x = fmaf(a.x, xv.y, acc[i][1].x); acc[i][1].y = fmaf(a.y, xv.y, acc[i][1].y);
        acc[i][2].x = fmaf(a.x, xv.z, acc[i][2].x); acc[i][2].y = fmaf(a.y, xv.z, acc[i][2].y);
        acc[i][3].x = fmaf(a.x, xv.w, acc[i][3].x); acc[i][3].y = fmaf(a.y, xv.w, acc[i][3].y);
      }
    }
    __syncthreads();
  }
  #pragma unroll
  for(int i=0;i<8;i++){
    int k=kb+kg*8+i;
    long o = (((long)d*256 + k)*256 + h)*128 + wg*4;
    *(float4*)&buf[o]   = make_float4(acc[i][0].x,acc[i][0].y,acc[i][1].x,acc[i][1].y);
    *(float4*)&buf[o+2] = make_float4(acc[i][2].x,acc[i][2].y,acc[i][3].x,acc[i][3].y);
  }
}

// ---------------- K2: forward 256-pt radix-4 DIF along q (rows 128..255 are zero; folded into load) -------
__launch_bounds__(256)
__global__ void k_ffty(c32* __restrict__ buf, const c32* __restrict__ T){
  __shared__ c32 tile[256*17];
  __shared__ c32 Ts[256];
  int tid=threadIdx.x;
  Ts[tid]=T[tid];
  int b=blockIdx.x;
  int d=b>>11, k=(b>>3)&255, w0=(b&7)*16;
  long base = (((long)d*256 + k)*256)*128 + w0;
  __syncthreads();
  #pragma unroll
  for(int it=0; it<4; it++){
    int idx = tid + it*256; int w = idx&15, j = idx>>4;
    c32 x0 = buf[base + (long)j*128 + w];
    c32 x1 = buf[base + (long)(j+64)*128 + w];
    tile[j*17+w] = cadd(x0,x1);
    c32 y1 = make_float2(x0.x + x1.y, x0.y - x1.x);   // x0 - i*x1
    c32 y2 = csub(x0,x1);
    c32 y3 = make_float2(x0.x - x1.y, x0.y + x1.x);   // x0 + i*x1
    tile[(j+64)*17+w]  = cmul(y1, Ts[j]);
    tile[(j+128)*17+w] = cmul(y2, Ts[(2*j)&255]);
    tile[(j+192)*17+w] = cmul(y3, Ts[(3*j)&255]);
  }
  __syncthreads();
  #pragma unroll
  for(int s=1;s<4;s++){
    int quarter = 64 >> (2*s);
    int m4 = quarter<<2;
    int sh = 2*s;
    #pragma unroll
    for(int it=0;it<4;it++){
      int idx=tid+it*256; int w=idx&15, bf=idx>>4;
      int g = bf/quarter, j = bf - g*quarter;
      int p0 = g*m4 + j;
      c32 x0=tile[p0*17+w], x1=tile[(p0+quarter)*17+w], x2=tile[(p0+2*quarter)*17+w], x3=tile[(p0+3*quarter)*17+w];
      c32 t0=cadd(x0,x2), t1=csub(x0,x2), t2=cadd(x1,x3), t3=csub(x1,x3);
      c32 y0=cadd(t0,t2);
      c32 y2=csub(t0,t2);
      c32 y1=make_float2(t1.x + t3.y, t1.y - t3.x);   // t1 - i*t3
      c32 y3=make_float2(t1.x - t3.y, t1.y + t3.x);   // t1 + i*t3
      tile[p0*17+w]=y0;
      tile[(p0+quarter)*17+w]  =cmul(y1, Ts[(j<<sh)&255]);
      tile[(p0+2*quarter)*17+w]=cmul(y2, Ts[((2*j)<<sh)&255]);
      tile[(p0+3*quarter)*17+w]=cmul(y3, Ts[((3*j)<<sh)&255]);
    }
    __syncthreads();
  }
  #pragma unroll
  for(int it=0;it<16;it++){
    int idx=tid+it*256; int w=idx&15, p=idx>>4;
    buf[base + (long)p*128 + w] = tile[p*17+w];
  }
}

// ---------------- K34: fused x-FFT * invpsf * x-IFFT per line; XCD-swizzled; pinned psf prefetch ----------
__launch_bounds__(256)
__global__ void k_fftx(c32* __restrict__ buf, const float* __restrict__ pre,
                       const float* __restrict__ pim, const c32* __restrict__ T){
  __shared__ float lre[16*272];
  __shared__ float lim[16*272];
  __shared__ c32 Ts[256];
  const int BR[16]={0,8,4,12,2,10,6,14,1,9,5,13,3,11,7,15};
  int tid=threadIdx.x;
  Ts[tid]=T[tid];
  int lane = tid & 63;
  int L = ((tid>>6)<<2) + (lane>>4);   // 0..15 : line within block
  int n1 = lane & 15;
  // XCD-aware swizzle: all 32 blocks of one k-plane land on one XCD -> psf rows L2-resident
  int b = blockIdx.x;
  int bs = ((b & 7) << 10) | (b >> 3);
  int k = bs >> 5;
  int q = ((bs & 31)<<3) + (L & 7);
  int d = L >> 3;
  long lbase = (((long)d*256 + k)*256 + q)*128;
  long prow = (((long)dr4(k))*256 + dr4(q))*256;
  int Lb = L*272;
  // ---- issue psf prefetch (32 loads) + data loads (8), then PIN the psf values so the
  //      compiler cannot sink the loads to the multiply site.
  const float* pb_re = pre + prow + n1;
  const float* pb_im = pim + prow + n1;
  c32 h[16];
  #pragma unroll
  for(int r=0;r<16;r++){ h[r].x = pb_re[16*BR[r]]; h[r].y = pb_im[16*BR[r]]; }
  c32 z[16];
  #pragma unroll
  for(int r=0;r<8;r++) z[r] = ntload(&buf[lbase + n1 + 16*r]);
  #pragma unroll
  for(int r=0;r<16;r++){ asm volatile("" : "+v"(h[r].x), "+v"(h[r].y)); }
  __syncthreads();
  // forward: FFT16 over n2 (upper half zero)
  dif16_pad<-1>(z);
  #pragma unroll
  for(int r=1;r<16;r++) z[r] = cmul(z[r], Ts[(n1*BR[r])&255]);
  #pragma unroll
  for(int r=0;r<16;r++){ int o = Lb + BR[r]*17 + n1; lre[o]=z[r].x; lim[o]=z[r].y; }
  __syncthreads();
  #pragma unroll
  for(int c=0;c<16;c++){ int o = Lb + n1*17 + c; z[c]=make_float2(lre[o], lim[o]); }
  // forward: FFT16 over n1 (lane now plays role k2)
  dif16<-1>(z);
  // pointwise multiply by prefetched invpsf (natural kx = n1 + 16*BR[r])
  #pragma unroll
  for(int r=0;r<16;r++) z[r] = cmul(z[r], h[r]);
  // inverse: IFFT16 over k1
  dit16(z);
  #pragma unroll
  for(int r=1;r<16;r++) z[r] = cmulc(z[r], Ts[(r*n1)&255]);
  __syncthreads();
  #pragma unroll
  for(int r=0;r<16;r++){ int o = Lb + r*17 + n1; lre[o]=z[r].x; lim[o]=z[r].y; }
  __syncthreads();
  #pragma unroll
  for(int c=0;c<16;c++){ int o = Lb + n1*17 + c; z[c]=make_float2(lre[o], lim[o]); }
  // inverse: IFFT16 over k2; only n = n1+16*n2 < 128 kept (even regs)
  dif16_crop<1>(z);
  const float s = 1.f/256.f;
  #pragma unroll
  for(int r=0;r<16;r+=2){
    int n2 = BR[r];
    ntstore(&buf[lbase + n1 + 16*n2], make_float2(z[r].x*s, z[r].y*s));
  }
}

// ---------------- K5: inverse 256-pt radix-4 DIT along q, crop q<128, in-place -----------------------------
__launch_bounds__(256)
__global__ void k_iffty(c32* __restrict__ buf, const c32* __restrict__ T){
  __shared__ c32 tile[256*17];
  __shared__ c32 Ts[256];
  int tid=threadIdx.x;
  Ts[tid]=T[tid];
  int b=blockIdx.x;
  int d=b>>11, k=(b>>3)&255, x0=(b&7)*16;
  long base = (((long)d*256 + k)*256)*128 + x0;
  __syncthreads();
  #pragma unroll
  for(int it=0;it<16;it++){
    int idx=tid+it*256; int w=idx&15, p=idx>>4;
    tile[p*17+w]=buf[base + (long)p*128 + w];
  }
  __syncthreads();
  #pragma unroll
  for(int s=0;s<3;s++){
    int quarter = 1<<(2*s);
    int m4 = quarter<<2;
    int sh = 2*(3-s);
    #pragma unroll
    for(int it=0;it<4;it++){
      int idx=tid+it*256; int w=idx&15, bf=idx>>4;
      int g=bf/quarter, j=bf-g*quarter;
      int p0=g*m4+j;
      c32 t0=tile[p0*17+w];
      c32 t1=cmulc(tile[(p0+quarter)*17+w],   Ts[(j<<sh)&255]);
      c32 t2=cmulc(tile[(p0+2*quarter)*17+w], Ts[((2*j)<<sh)&255]);
      c32 t3=cmulc(tile[(p0+3*quarter)*17+w], Ts[((3*j)<<sh)&255]);
      c32 y0 = make_float2(t0.x+t1.x+t2.x+t3.x, t0.y+t1.y+t2.y+t3.y);
      c32 y1 = make_float2(t0.x - t1.y - t2.x + t3.y, t0.y + t1.x - t2.y - t3.x);
      c32 y2 = make_float2(t0.x - t1.x + t2.x - t3.x, t0.y - t1.y + t2.y - t3.y);
      c32 y3 = make_float2(t0.x + t1.y - t2.x - t3.y, t0.y - t1.x - t2.y + t3.x);
      tile[p0*17+w]=y0; tile[(p0+quarter)*17+w]=y1; tile[(p0+2*quarter)*17+w]=y2; tile[(p0+3*quarter)*17+w]=y3;
    }
    __syncthreads();
  }
  const float sc = 1.f/256.f;
  #pragma unroll
  for(int it=0;it<4;it++){
    int idx=tid+it*256; int w=idx&15, j=idx>>4;
    c32 t0=tile[j*17+w];
    c32 t1=cmulc(tile[(j+64)*17+w],  Ts[j]);
    c32 t2=cmulc(tile[(j+128)*17+w], Ts[(2*j)&255]);
    c32 t3=cmulc(tile[(j+192)*17+w], Ts[(3*j)&255]);
    c32 y0 = make_float2((t0.x+t1.x+t2.x+t3.x)*sc, (t0.y+t1.y+t2.y+t3.y)*sc);
    c32 y1 = make_float2((t0.x - t1.y - t2.x + t3.y)*sc, (t0.y + t1.x - t2.y - t3.x)*sc);
    buf[base + (long)j*128 + w] = y0;
    buf[base + (long)(j+64)*128 + w] = y1;
  }
}

// ---------------- K6: inverse 256-pt DIT along k (z), crop z<128, magnitude, fused mtxi matmul -> out -----
__launch_bounds__(256)
__global__ void k_back(c32* __restrict__ buf, const float* __restrict__ mtxi,
                       const c32* __restrict__ T, float* __restrict__ out){
  __shared__ c32 tile[256*17];     // FFT tile; reused as mtxi chunk [128 t][68] floats in phase 2
  __shared__ float magl[128*16];   // mag[t][x] for this block's 16 x
  __shared__ c32 Ts[256];
  int tid=threadIdx.x;
  Ts[tid]=T[tid];
  int b=blockIdx.x;
  int d=b>>10, y=(b>>3)&127, x0=(b&7)*16;
  __syncthreads();
  #pragma unroll
  for(int it=0;it<16;it++){
    int idx=tid+it*256; int w=idx&15, p=idx>>4;
    tile[p*17+w]=buf[(((long)d*256 + p)*256 + y)*128 + x0 + w];
  }
  __syncthreads();
  #pragma unroll
  for(int s=0;s<3;s++){
    int quarter = 1<<(2*s);
    int m4 = quarter<<2;
    int sh = 2*(3-s);
    #pragma unroll
    for(int it=0;it<4;it++){
      int idx=tid+it*256; int w=idx&15, bf=idx>>4;
      int g=bf/quarter, j=bf-g*quarter;
      int p0=g*m4+j;
      c32 t0=tile[p0*17+w];
      c32 t1=cmulc(tile[(p0+quarter)*17+w],   Ts[(j<<sh)&255]);
      c32 t2=cmulc(tile[(p0+2*quarter)*17+w], Ts[((2*j)<<sh)&255]);
      c32 t3=cmulc(tile[(p0+3*quarter)*17+w], Ts[((3*j)<<sh)&255]);
      c32 y0 = make_float2(t0.x+t1.x+t2.x+t3.x, t0.y+t1.y+t2.y+t3.y);
      c32 y1 = make_float2(t0.x - t1.y - t2.x + t3.y, t0.y + t1.x - t2.y - t3.x);
      c32 y2 = make_float2(t0.x - t1.x + t2.x - t3.x, t0.y - t1.y + t2.y - t3.y);
      c32 y3 = make_float2(t0.x + t1.y - t2.x - t3.y, t0.y - t1.x - t2.y + t3.x);
      tile[p0*17+w]=y0; tile[(p0+quarter)*17+w]=y1; tile[(p0+2*quarter)*17+w]=y2; tile[(p0+3*quarter)*17+w]=y3;
    }
    __syncthreads();
  }
  const float sc = 1.f/256.f;
  #pragma unroll
  for(int it=0;it<4;it++){
    int idx=tid+it*256; int w=idx&15, j=idx>>4;
    c32 t0=tile[j*17+w];
    c32 t1=cmulc(tile[(j+64)*17+w],  Ts[j]);
    c32 t2=cmulc(tile[(j+128)*17+w], Ts[(2*j)&255]);
    c32 t3=cmulc(tile[(j+192)*17+w], Ts[(3*j)&255]);
    float y0r = t0.x+t1.x+t2.x+t3.x, y0i = t0.y+t1.y+t2.y+t3.y;
    float y1r = t0.x - t1.y - t2.x + t3.y, y1i = t0.y + t1.x - t2.y - t3.x;
    magl[j*16 + w]      = sqrtf(y0r*y0r + y0i*y0i) * sc;
    magl[(j+64)*16 + w] = sqrtf(y1r*y1r + y1i*y1i) * sc;
  }
  __syncthreads();
  // ---- phase 2: out[d, m, y, x0+xg*4..+3] = sum_t mtxi[m,t] * magl[t][x]
  float* mt = (float*)tile;        // [128 t][68] chunk of 64 m (33 KB <= 34.8 KB)
  int xg = tid&3, mg = tid>>2;     // 64 mg x 4 xg
  #pragma unroll
  for(int c=0;c<2;c++){
    #pragma unroll
    for(int it=0;it<32;it++){
      int idx=tid+it*256; int t=idx&127, mm=idx>>7;
      mt[t*68+mm] = mtxi[(c*64+mm)*128 + t];
    }
    __syncthreads();
    float4 a = make_float4(0.f,0.f,0.f,0.f);
    #pragma unroll 4
    for(int t=0;t<128;t++){
      float mv = mt[t*68 + mg];
      float4 g = *(const float4*)&magl[t*16 + xg*4];
      a.x = fmaf(mv, g.x, a.x); a.y = fmaf(mv, g.y, a.y);
      a.z = fmaf(mv, g.z, a.z); a.w = fmaf(mv, g.w, a.w);
    }
    int m_ = c*64 + mg;
    *(float4*)&out[(((long)d*128 + m_)*128 + y)*128 + x0 + xg*4] = a;
    __syncthreads();
  }
}

extern "C" void kernel_launch(void* const* d_in, const int* in_sizes, int n_in,
                              void* d_out, int out_size, void* d_ws, size_t ws_size,
                              hipStream_t stream) {
  const float* feat=(const float*)d_in[0];
  const float* wave=(const float*)d_in[1];
  const float* mtx =(const float*)d_in[2];
  const float* mtxi=(const float*)d_in[3];
  const float* pre =(const float*)d_in[4];
  const float* pim =(const float*)d_in[5];
  const int*   tbes=(const int*)d_in[6];
  float* out=(float*)d_out;
  char* ws=(char*)d_ws;
  c32* A   = (c32*)ws;               // 256*96*8      = 196608 B
  c32* T   = (c32*)(ws + 196608);    // 256*8         = 2048 B
  c32* buf = (c32*)(ws + 262144);    // 2*256*256*128*8 = 134217728 B

  int K = in_sizes[1] / 2;           // wave_2x1xk -> k taps
  int P = (K & 1) ? (K/2) : (K/2 - 1);

  hipLaunchKernelGGL(k_setup, dim3(96),   dim3(256), 0, stream, mtx, wave, tbes, A, T, K, P);
  hipLaunchKernelGGL(k_front, dim3(1024), dim3(256), 0, stream, feat, A, buf);
  hipLaunchKernelGGL(k_ffty,  dim3(4096), dim3(256), 0, stream, buf, T);
  hipLaunchKernelGGL(k_fftx,  dim3(8192), dim3(256), 0, stream, buf, pre, pim, T);
  hipLaunchKernelGGL(k_iffty, dim3(4096), dim3(256), 0, stream, buf, T);
  hipLaunchKernelGGL(k_back,  dim3(2048), dim3(256), 0, stream, buf, mtxi, T, out);
}

// Round 9
// 245.030 us; speedup vs baseline: 1.0450x; 1.0113x over previous
//
#include <hip/hip_runtime.h>
#include <math.h>

typedef float2 c32;

__device__ __forceinline__ c32 cadd(c32 a, c32 b){ return make_float2(a.x+b.x, a.y+b.y); }
__device__ __forceinline__ c32 csub(c32 a, c32 b){ return make_float2(a.x-b.x, a.y-b.y); }
__device__ __forceinline__ c32 cmul(c32 a, c32 b){ return make_float2(fmaf(a.x,b.x,-a.y*b.y), fmaf(a.x,b.y,a.y*b.x)); }
// a * conj(b)
__device__ __forceinline__ c32 cmulc(c32 a, c32 b){ return make_float2(fmaf(a.x,b.x, a.y*b.y), fmaf(a.y,b.x,-a.x*b.y)); }

__device__ __forceinline__ c32 ntload(const c32* p){
  double v = __builtin_nontemporal_load(reinterpret_cast<const double*>(p));
  union { double d; float f[2]; } u; u.d = v;
  return make_float2(u.f[0], u.f[1]);
}
__device__ __forceinline__ void ntstore(c32* p, c32 v){
  union { double d; float f[2]; } u; u.f[0]=v.x; u.f[1]=v.y;
  __builtin_nontemporal_store(u.d, reinterpret_cast<double*>(p));
}

__device__ __forceinline__ int dr4(int p){
  return ((p&3)<<6) | (((p>>2)&3)<<4) | (((p>>4)&3)<<2) | ((p>>6)&3);
}

// 16-pt radix-2 DIF, natural input, output reg r holds freq brev4(r).
template<int S>
__device__ __forceinline__ void dif16(c32 (&z)[16]){
  const float C1=0.92387953251128675613f, S1=0.38268343236508977173f, C2=0.70710678118654752440f;
  const float sg = (float)S;
  const c32 W[8] = { {1.f,0.f},{C1,sg*S1},{C2,sg*C2},{S1,sg*C1},{0.f,sg},{-S1,sg*C1},{-C2,sg*C2},{-C1,sg*S1} };
  #pragma unroll
  for(int j=0;j<8;j++){ c32 a=z[j], b=z[j+8]; z[j]=cadd(a,b); z[j+8]=cmul(csub(a,b), W[j]); }
  #pragma unroll
  for(int blk=0; blk<16; blk+=8){
    #pragma unroll
    for(int j=0;j<4;j++){ c32 a=z[blk+j], b=z[blk+j+4]; z[blk+j]=cadd(a,b); z[blk+j+4]=cmul(csub(a,b), W[2*j]); }
  }
  #pragma unroll
  for(int blk=0; blk<16; blk+=4){
    c32 a=z[blk], b=z[blk+2]; z[blk]=cadd(a,b); z[blk+2]=csub(a,b);
    c32 a1=z[blk+1], b1=z[blk+3]; c32 d=csub(a1,b1);
    z[blk+1]=cadd(a1,b1);
    z[blk+3]= (S<0)? make_float2(d.y,-d.x) : make_float2(-d.y,d.x);
  }
  #pragma unroll
  for(int blk=0; blk<16; blk+=2){ c32 a=z[blk], b=z[blk+1]; z[blk]=cadd(a,b); z[blk+1]=csub(a,b); }
}

// Same as dif16 but input z[8..15] are implicitly ZERO (only z[0..7] read).
template<int S>
__device__ __forceinline__ void dif16_pad(c32 (&z)[16]){
  const float C1=0.92387953251128675613f, S1=0.38268343236508977173f, C2=0.70710678118654752440f;
  const float sg = (float)S;
  const c32 W[8] = { {1.f,0.f},{C1,sg*S1},{C2,sg*C2},{S1,sg*C1},{0.f,sg},{-S1,sg*C1},{-C2,sg*C2},{-C1,sg*S1} };
  z[8]=z[0];
  #pragma unroll
  for(int j=1;j<8;j++) z[j+8]=cmul(z[j], W[j]);
  #pragma unroll
  for(int blk=0; blk<16; blk+=8){
    #pragma unroll
    for(int j=0;j<4;j++){ c32 a=z[blk+j], b=z[blk+j+4]; z[blk+j]=cadd(a,b); z[blk+j+4]=cmul(csub(a,b), W[2*j]); }
  }
  #pragma unroll
  for(int blk=0; blk<16; blk+=4){
    c32 a=z[blk], b=z[blk+2]; z[blk]=cadd(a,b); z[blk+2]=csub(a,b);
    c32 a1=z[blk+1], b1=z[blk+3]; c32 d=csub(a1,b1);
    z[blk+1]=cadd(a1,b1);
    z[blk+3]= (S<0)? make_float2(d.y,-d.x) : make_float2(-d.y,d.x);
  }
  #pragma unroll
  for(int blk=0; blk<16; blk+=2){ c32 a=z[blk], b=z[blk+1]; z[blk]=cadd(a,b); z[blk+1]=csub(a,b); }
}

// Same as dif16 but only EVEN output regs are produced (odd regs garbage) — for cropped stores.
template<int S>
__device__ __forceinline__ void dif16_crop(c32 (&z)[16]){
  const float C1=0.92387953251128675613f, S1=0.38268343236508977173f, C2=0.70710678118654752440f;
  const float sg = (float)S;
  const c32 W[8] = { {1.f,0.f},{C1,sg*S1},{C2,sg*C2},{S1,sg*C1},{0.f,sg},{-S1,sg*C1},{-C2,sg*C2},{-C1,sg*S1} };
  #pragma unroll
  for(int j=0;j<8;j++){ c32 a=z[j], b=z[j+8]; z[j]=cadd(a,b); z[j+8]=cmul(csub(a,b), W[j]); }
  #pragma unroll
  for(int blk=0; blk<16; blk+=8){
    #pragma unroll
    for(int j=0;j<4;j++){ c32 a=z[blk+j], b=z[blk+j+4]; z[blk+j]=cadd(a,b); z[blk+j+4]=cmul(csub(a,b), W[2*j]); }
  }
  #pragma unroll
  for(int blk=0; blk<16; blk+=4){
    c32 a=z[blk], b=z[blk+2]; z[blk]=cadd(a,b); z[blk+2]=csub(a,b);
    c32 a1=z[blk+1], b1=z[blk+3]; c32 d=csub(a1,b1);
    z[blk+1]=cadd(a1,b1);
    z[blk+3]= (S<0)? make_float2(d.y,-d.x) : make_float2(-d.y,d.x);
  }
  #pragma unroll
  for(int blk=0; blk<16; blk+=2){ z[blk]=cadd(z[blk], z[blk+1]); }   // even outputs only
}

// 16-pt radix-2 DIT, input reg r holds X[brev4(r)], natural output, W=e^{+2pi i/16}.
__device__ __forceinline__ void dit16(c32 (&z)[16]){
  const float C1=0.92387953251128675613f, S1=0.38268343236508977173f, C2=0.70710678118654752440f;
  const c32 Wc[8] = { {1.f,0.f},{C1,S1},{C2,C2},{S1,C1},{0.f,1.f},{-S1,C1},{-C2,C2},{-C1,S1} };
  #pragma unroll
  for(int p=0;p<16;p+=2){ c32 a=z[p], b=z[p+1]; z[p]=cadd(a,b); z[p+1]=csub(a,b); }
  #pragma unroll
  for(int g=0;g<16;g+=4){
    c32 t=z[g+2]; z[g+2]=csub(z[g],t); z[g]=cadd(z[g],t);
    c32 u=z[g+3]; c32 t1=make_float2(-u.y,u.x); z[g+3]=csub(z[g+1],t1); z[g+1]=cadd(z[g+1],t1);
  }
  #pragma unroll
  for(int g=0;g<16;g+=8){
    #pragma unroll
    for(int j=0;j<4;j++){ c32 t=cmul(z[g+4+j], Wc[2*j]); z[g+4+j]=csub(z[g+j],t); z[g+j]=cadd(z[g+j],t); }
  }
  #pragma unroll
  for(int j=0;j<8;j++){ c32 t=cmul(z[8+j], Wc[j]); z[8+j]=csub(z[j],t); z[j]=cadd(z[j],t); }
}

// ---------------- K0: build A (256x96 complex, rows stored digit-reversed) + twiddle table ----------------
__launch_bounds__(256)
__global__ void k_setup(const float* __restrict__ mtx, const float* __restrict__ wave,
                        const int* __restrict__ tbes, c32* __restrict__ A, c32* __restrict__ T,
                        int K, int P){
  __shared__ double2 w256[256];
  __shared__ double gre[128];
  __shared__ double gim[128];
  int tid=threadIdx.x; int v=blockIdx.x;
  double ang = -6.2831853071795864769252867665590 * (double)tid / 256.0;
  w256[tid]=make_double2(cos(ang), sin(ang));
  if(v==0) T[tid]=make_float2((float)w256[tid].x,(float)w256[tid].y);
  __syncthreads();
  if(tid<128){
    int tbe=tbes[0];
    double sr=0.0, si=0.0;
    for(int t=0;t<128;t++){
      int jj = v + tbe + P - t;
      if(jj>=0 && jj<K){
        double mv=(double)mtx[tid*128+t];
        sr += mv*(double)wave[jj];
        si += mv*(double)wave[K+jj];
      }
    }
    gre[tid]=sr; gim[tid]=si;
  }
  __syncthreads();
  double ar=0.0, ai=0.0;
  int k=tid;
  for(int m=0;m<128;m++){
    double2 f=w256[(k*m)&255];
    ar += f.x*gre[m] - f.y*gim[m];
    ai += f.x*gim[m] + f.y*gre[m];
  }
  A[(long)dr4(k)*96 + v] = make_float2((float)ar,(float)ai);
}

// ---------------- K1: fused pad+conv+mtx+zeropad+FFT_z; kb-loop inside so feat is read once per block -----
// grid 512: b -> kbh=b&1, h=(b>>1)&127, d=b>>8; handles kb in {2*kbh, 2*kbh+1}.
__launch_bounds__(256)
__global__ void k_front(const float* __restrict__ feat, const c32* __restrict__ A, c32* __restrict__ buf){
  __shared__ __align__(16) float Xs[48*128];
  __shared__ __align__(16) c32 As[64*48];
  int tid=threadIdx.x; int b=blockIdx.x;
  int kbh=b&1, h=(b>>1)&127, d=b>>8;
  int kg=tid>>5, wg=tid&31;
  #pragma unroll
  for(int kbi=0; kbi<2; kbi++){
    int kb=(kbh*2+kbi)*64;
    c32 acc[8][4];
    #pragma unroll
    for(int i=0;i<8;i++){
      #pragma unroll
      for(int j=0;j<4;j++) acc[i][j]=make_float2(0.f,0.f);
    }
    for(int vc=0; vc<2; vc++){
      #pragma unroll
      for(int i=0;i<6;i++){
        int idx=tid+i*256;
        int v=idx>>5, w4=idx&31;
        *(float4*)&Xs[v*128 + w4*4] = *(const float4*)&feat[(((long)d*96 + vc*48+v)*128 + h)*128 + w4*4];
      }
      #pragma unroll
      for(int i=0;i<6;i++){
        int idx=tid+i*256;
        int kk=idx/24, rem=idx-kk*24;
        *(float4*)&As[kk*48 + rem*2] = *(const float4*)&A[(long)(kb+kk)*96 + vc*48 + rem*2];
      }
      __syncthreads();
      #pragma unroll 4
      for(int vv=0; vv<48; vv++){
        float4 xv = *(const float4*)&Xs[vv*128 + wg*4];
        #pragma unroll
        for(int i=0;i<8;i++){
          c32 a = As[(kg*8+i)*48 + vv];
          acc[i][0].x = fmaf(a.x, xv.x, acc[i][0].x); acc[i][0].y = fmaf(a.y, xv.x, acc[i][0].y);
          acc[i][1].x = fmaf(a.x, xv.y, acc[i][1].x); acc[i][1].y = fmaf(a.y, xv.y, acc[i][1].y);
          acc[i][2].x = fmaf(a.x, xv.z, acc[i][2].x); acc[i][2].y = fmaf(a.y, xv.z, acc[i][2].y);
          acc[i][3].x = fmaf(a.x, xv.w, acc[i][3].x); acc[i][3].y = fmaf(a.y, xv.w, acc[i][3].y);
        }
      }
      __syncthreads();
    }
    #pragma unroll
    for(int i=0;i<8;i++){
      int k=kb+kg*8+i;
      long o = (((long)d*256 + k)*256 + h)*128 + wg*4;
      *(float4*)&buf[o]   = make_float4(acc[i][0].x,acc[i][0].y,acc[i][1].x,acc[i][1].y);
      *(float4*)&buf[o+2] = make_float4(acc[i][2].x,acc[i][2].y,acc[i][3].x,acc[i][3].y);
    }
  }
}

// ---------------- K2: forward 256-pt radix-4 DIF along q (rows 128..255 are zero; folded into load) -------
__launch_bounds__(256)
__global__ void k_ffty(c32* __restrict__ buf, const c32* __restrict__ T){
  __shared__ c32 tile[256*17];
  __shared__ c32 Ts[256];
  int tid=threadIdx.x;
  Ts[tid]=T[tid];
  int b=blockIdx.x;
  int d=b>>11, k=(b>>3)&255, w0=(b&7)*16;
  long base = (((long)d*256 + k)*256)*128 + w0;
  __syncthreads();
  #pragma unroll
  for(int it=0; it<4; it++){
    int idx = tid + it*256; int w = idx&15, j = idx>>4;
    c32 x0 = buf[base + (long)j*128 + w];
    c32 x1 = buf[base + (long)(j+64)*128 + w];
    tile[j*17+w] = cadd(x0,x1);
    c32 y1 = make_float2(x0.x + x1.y, x0.y - x1.x);   // x0 - i*x1
    c32 y2 = csub(x0,x1);
    c32 y3 = make_float2(x0.x - x1.y, x0.y + x1.x);   // x0 + i*x1
    tile[(j+64)*17+w]  = cmul(y1, Ts[j]);
    tile[(j+128)*17+w] = cmul(y2, Ts[(2*j)&255]);
    tile[(j+192)*17+w] = cmul(y3, Ts[(3*j)&255]);
  }
  __syncthreads();
  #pragma unroll
  for(int s=1;s<4;s++){
    int quarter = 64 >> (2*s);
    int m4 = quarter<<2;
    int sh = 2*s;
    #pragma unroll
    for(int it=0;it<4;it++){
      int idx=tid+it*256; int w=idx&15, bf=idx>>4;
      int g = bf/quarter, j = bf - g*quarter;
      int p0 = g*m4 + j;
      c32 x0=tile[p0*17+w], x1=tile[(p0+quarter)*17+w], x2=tile[(p0+2*quarter)*17+w], x3=tile[(p0+3*quarter)*17+w];
      c32 t0=cadd(x0,x2), t1=csub(x0,x2), t2=cadd(x1,x3), t3=csub(x1,x3);
      c32 y0=cadd(t0,t2);
      c32 y2=csub(t0,t2);
      c32 y1=make_float2(t1.x + t3.y, t1.y - t3.x);   // t1 - i*t3
      c32 y3=make_float2(t1.x - t3.y, t1.y + t3.x);   // t1 + i*t3
      tile[p0*17+w]=y0;
      tile[(p0+quarter)*17+w]  =cmul(y1, Ts[(j<<sh)&255]);
      tile[(p0+2*quarter)*17+w]=cmul(y2, Ts[((2*j)<<sh)&255]);
      tile[(p0+3*quarter)*17+w]=cmul(y3, Ts[((3*j)<<sh)&255]);
    }
    __syncthreads();
  }
  #pragma unroll
  for(int it=0;it<16;it++){
    int idx=tid+it*256; int w=idx&15, p=idx>>4;
    buf[base + (long)p*128 + w] = tile[p*17+w];
  }
}

// ---------------- K34: fused x-FFT * invpsf * x-IFFT per line; XCD-swizzled; pinned psf prefetch;
//                  wave-synchronous transposes (line regions are 16-lane private) ------------------------
__launch_bounds__(256)
__global__ void k_fftx(c32* __restrict__ buf, const float* __restrict__ pre,
                       const float* __restrict__ pim, const c32* __restrict__ T){
  __shared__ float lre[16*272];
  __shared__ float lim[16*272];
  __shared__ c32 Ts[256];
  const int BR[16]={0,8,4,12,2,10,6,14,1,9,5,13,3,11,7,15};
  int tid=threadIdx.x;
  Ts[tid]=T[tid];
  int lane = tid & 63;
  int L = ((tid>>6)<<2) + (lane>>4);   // 0..15 : line within block
  int n1 = lane & 15;
  // XCD-aware swizzle: all 32 blocks of one k-plane land on one XCD -> psf rows L2-resident
  int b = blockIdx.x;
  int bs = ((b & 7) << 10) | (b >> 3);
  int k = bs >> 5;
  int q = ((bs & 31)<<3) + (L & 7);
  int d = L >> 3;
  long lbase = (((long)d*256 + k)*256 + q)*128;
  long prow = (((long)dr4(k))*256 + dr4(q))*256;
  int Lb = L*272;
  // ---- issue psf prefetch (32 loads) + data loads (8), then PIN the psf values so the
  //      compiler cannot sink the loads to the multiply site.
  const float* pb_re = pre + prow + n1;
  const float* pb_im = pim + prow + n1;
  c32 h[16];
  #pragma unroll
  for(int r=0;r<16;r++){ h[r].x = pb_re[16*BR[r]]; h[r].y = pb_im[16*BR[r]]; }
  c32 z[16];
  #pragma unroll
  for(int r=0;r<8;r++) z[r] = ntload(&buf[lbase + n1 + 16*r]);
  #pragma unroll
  for(int r=0;r<16;r++){ asm volatile("" : "+v"(h[r].x), "+v"(h[r].y)); }
  __syncthreads();                     // Ts visible; the ONLY block barrier
  // forward: FFT16 over n2 (upper half zero)
  dif16_pad<-1>(z);
  #pragma unroll
  for(int r=1;r<16;r++) z[r] = cmul(z[r], Ts[(n1*BR[r])&255]);
  #pragma unroll
  for(int r=0;r<16;r++){ int o = Lb + BR[r]*17 + n1; lre[o]=z[r].x; lim[o]=z[r].y; }
  __builtin_amdgcn_wave_barrier();     // wave-sync: line region private to this wave's 16 lanes
  #pragma unroll
  for(int c=0;c<16;c++){ int o = Lb + n1*17 + c; z[c]=make_float2(lre[o], lim[o]); }
  // forward: FFT16 over n1 (lane now plays role k2)
  dif16<-1>(z);
  // pointwise multiply by prefetched invpsf (natural kx = n1 + 16*BR[r])
  #pragma unroll
  for(int r=0;r<16;r++) z[r] = cmul(z[r], h[r]);
  // inverse: IFFT16 over k1
  dit16(z);
  #pragma unroll
  for(int r=1;r<16;r++) z[r] = cmulc(z[r], Ts[(r*n1)&255]);
  __builtin_amdgcn_wave_barrier();
  #pragma unroll
  for(int r=0;r<16;r++){ int o = Lb + r*17 + n1; lre[o]=z[r].x; lim[o]=z[r].y; }
  __builtin_amdgcn_wave_barrier();
  #pragma unroll
  for(int c=0;c<16;c++){ int o = Lb + n1*17 + c; z[c]=make_float2(lre[o], lim[o]); }
  // inverse: IFFT16 over k2; only n = n1+16*n2 < 128 kept (even regs)
  dif16_crop<1>(z);
  const float s = 1.f/256.f;
  #pragma unroll
  for(int r=0;r<16;r+=2){
    int n2 = BR[r];
    ntstore(&buf[lbase + n1 + 16*n2], make_float2(z[r].x*s, z[r].y*s));
  }
}

// ---------------- K5: inverse 256-pt radix-4 DIT along q, crop q<128, in-place -----------------------------
__launch_bounds__(256)
__global__ void k_iffty(c32* __restrict__ buf, const c32* __restrict__ T){
  __shared__ c32 tile[256*17];
  __shared__ c32 Ts[256];
  int tid=threadIdx.x;
  Ts[tid]=T[tid];
  int b=blockIdx.x;
  int d=b>>11, k=(b>>3)&255, x0=(b&7)*16;
  long base = (((long)d*256 + k)*256)*128 + x0;
  __syncthreads();
  #pragma unroll
  for(int it=0;it<16;it++){
    int idx=tid+it*256; int w=idx&15, p=idx>>4;
    tile[p*17+w]=buf[base + (long)p*128 + w];
  }
  __syncthreads();
  #pragma unroll
  for(int s=0;s<3;s++){
    int quarter = 1<<(2*s);
    int m4 = quarter<<2;
    int sh = 2*(3-s);
    #pragma unroll
    for(int it=0;it<4;it++){
      int idx=tid+it*256; int w=idx&15, bf=idx>>4;
      int g=bf/quarter, j=bf-g*quarter;
      int p0=g*m4+j;
      c32 t0=tile[p0*17+w];
      c32 t1=cmulc(tile[(p0+quarter)*17+w],   Ts[(j<<sh)&255]);
      c32 t2=cmulc(tile[(p0+2*quarter)*17+w], Ts[((2*j)<<sh)&255]);
      c32 t3=cmulc(tile[(p0+3*quarter)*17+w], Ts[((3*j)<<sh)&255]);
      c32 y0 = make_float2(t0.x+t1.x+t2.x+t3.x, t0.y+t1.y+t2.y+t3.y);
      c32 y1 = make_float2(t0.x - t1.y - t2.x + t3.y, t0.y + t1.x - t2.y - t3.x);
      c32 y2 = make_float2(t0.x - t1.x + t2.x - t3.x, t0.y - t1.y + t2.y - t3.y);
      c32 y3 = make_float2(t0.x + t1.y - t2.x - t3.y, t0.y - t1.x - t2.y + t3.x);
      tile[p0*17+w]=y0; tile[(p0+quarter)*17+w]=y1; tile[(p0+2*quarter)*17+w]=y2; tile[(p0+3*quarter)*17+w]=y3;
    }
    __syncthreads();
  }
  const float sc = 1.f/256.f;
  #pragma unroll
  for(int it=0;it<4;it++){
    int idx=tid+it*256; int w=idx&15, j=idx>>4;
    c32 t0=tile[j*17+w];
    c32 t1=cmulc(tile[(j+64)*17+w],  Ts[j]);
    c32 t2=cmulc(tile[(j+128)*17+w], Ts[(2*j)&255]);
    c32 t3=cmulc(tile[(j+192)*17+w], Ts[(3*j)&255]);
    c32 y0 = make_float2((t0.x+t1.x+t2.x+t3.x)*sc, (t0.y+t1.y+t2.y+t3.y)*sc);
    c32 y1 = make_float2((t0.x - t1.y - t2.x + t3.y)*sc, (t0.y + t1.x - t2.y - t3.x)*sc);
    buf[base + (long)j*128 + w] = y0;
    buf[base + (long)(j+64)*128 + w] = y1;
  }
}

// ---------------- K6: inverse 256-pt DIT along k (z), crop z<128, magnitude, fused mtxi matmul -> out -----
__launch_bounds__(256)
__global__ void k_back(c32* __restrict__ buf, const float* __restrict__ mtxi,
                       const c32* __restrict__ T, float* __restrict__ out){
  __shared__ c32 tile[256*17];     // FFT tile; reused as mtxi chunk [128 t][68] floats in phase 2
  __shared__ float magl[128*16];   // mag[t][x] for this block's 16 x
  __shared__ c32 Ts[256];
  int tid=threadIdx.x;
  Ts[tid]=T[tid];
  int b=blockIdx.x;
  int d=b>>10, y=(b>>3)&127, x0=(b&7)*16;
  __syncthreads();
  #pragma unroll
  for(int it=0;it<16;it++){
    int idx=tid+it*256; int w=idx&15, p=idx>>4;
    tile[p*17+w]=buf[(((long)d*256 + p)*256 + y)*128 + x0 + w];
  }
  __syncthreads();
  #pragma unroll
  for(int s=0;s<3;s++){
    int quarter = 1<<(2*s);
    int m4 = quarter<<2;
    int sh = 2*(3-s);
    #pragma unroll
    for(int it=0;it<4;it++){
      int idx=tid+it*256; int w=idx&15, bf=idx>>4;
      int g=bf/quarter, j=bf-g*quarter;
      int p0=g*m4+j;
      c32 t0=tile[p0*17+w];
      c32 t1=cmulc(tile[(p0+quarter)*17+w],   Ts[(j<<sh)&255]);
      c32 t2=cmulc(tile[(p0+2*quarter)*17+w], Ts[((2*j)<<sh)&255]);
      c32 t3=cmulc(tile[(p0+3*quarter)*17+w], Ts[((3*j)<<sh)&255]);
      c32 y0 = make_float2(t0.x+t1.x+t2.x+t3.x, t0.y+t1.y+t2.y+t3.y);
      c32 y1 = make_float2(t0.x - t1.y - t2.x + t3.y, t0.y + t1.x - t2.y - t3.x);
      c32 y2 = make_float2(t0.x - t1.x + t2.x - t3.x, t0.y - t1.y + t2.y - t3.y);
      c32 y3 = make_float2(t0.x + t1.y - t2.x - t3.y, t0.y - t1.x - t2.y + t3.x);
      tile[p0*17+w]=y0; tile[(p0+quarter)*17+w]=y1; tile[(p0+2*quarter)*17+w]=y2; tile[(p0+3*quarter)*17+w]=y3;
    }
    __syncthreads();
  }
  const float sc = 1.f/256.f;
  #pragma unroll
  for(int it=0;it<4;it++){
    int idx=tid+it*256; int w=idx&15, j=idx>>4;
    c32 t0=tile[j*17+w];
    c32 t1=cmulc(tile[(j+64)*17+w],  Ts[j]);
    c32 t2=cmulc(tile[(j+128)*17+w], Ts[(2*j)&255]);
    c32 t3=cmulc(tile[(j+192)*17+w], Ts[(3*j)&255]);
    float y0r = t0.x+t1.x+t2.x+t3.x, y0i = t0.y+t1.y+t2.y+t3.y;
    float y1r = t0.x - t1.y - t2.x + t3.y, y1i = t0.y + t1.x - t2.y - t3.x;
    magl[j*16 + w]      = sqrtf(y0r*y0r + y0i*y0i) * sc;
    magl[(j+64)*16 + w] = sqrtf(y1r*y1r + y1i*y1i) * sc;
  }
  __syncthreads();
  // ---- phase 2: out[d, m, y, x0+xg*4..+3] = sum_t mtxi[m,t] * magl[t][x]
  float* mt = (float*)tile;        // [128 t][68] chunk of 64 m (33 KB <= 34.8 KB)
  int xg = tid&3, mg = tid>>2;     // 64 mg x 4 xg
  #pragma unroll
  for(int c=0;c<2;c++){
    #pragma unroll
    for(int it=0;it<32;it++){
      int idx=tid+it*256; int t=idx&127, mm=idx>>7;
      mt[t*68+mm] = mtxi[(c*64+mm)*128 + t];
    }
    __syncthreads();
    float4 a = make_float4(0.f,0.f,0.f,0.f);
    #pragma unroll 4
    for(int t=0;t<128;t++){
      float mv = mt[t*68 + mg];
      float4 g = *(const float4*)&magl[t*16 + xg*4];
      a.x = fmaf(mv, g.x, a.x); a.y = fmaf(mv, g.y, a.y);
      a.z = fmaf(mv, g.z, a.z); a.w = fmaf(mv, g.w, a.w);
    }
    int m_ = c*64 + mg;
    *(float4*)&out[(((long)d*128 + m_)*128 + y)*128 + x0 + xg*4] = a;
    __syncthreads();
  }
}

extern "C" void kernel_launch(void* const* d_in, const int* in_sizes, int n_in,
                              void* d_out, int out_size, void* d_ws, size_t ws_size,
                              hipStream_t stream) {
  const float* feat=(const float*)d_in[0];
  const float* wave=(const float*)d_in[1];
  const float* mtx =(const float*)d_in[2];
  const float* mtxi=(const float*)d_in[3];
  const float* pre =(const float*)d_in[4];
  const float* pim =(const float*)d_in[5];
  const int*   tbes=(const int*)d_in[6];
  float* out=(float*)d_out;
  char* ws=(char*)d_ws;
  c32* A   = (c32*)ws;               // 256*96*8      = 196608 B
  c32* T   = (c32*)(ws + 196608);    // 256*8         = 2048 B
  c32* buf = (c32*)(ws + 262144);    // 2*256*256*128*8 = 134217728 B

  int K = in_sizes[1] / 2;           // wave_2x1xk -> k taps
  int P = (K & 1) ? (K/2) : (K/2 - 1);

  hipLaunchKernelGGL(k_setup, dim3(96),   dim3(256), 0, stream, mtx, wave, tbes, A, T, K, P);
  hipLaunchKernelGGL(k_front, dim3(512),  dim3(256), 0, stream, feat, A, buf);
  hipLaunchKernelGGL(k_ffty,  dim3(4096), dim3(256), 0, stream, buf, T);
  hipLaunchKernelGGL(k_fftx,  dim3(8192), dim3(256), 0, stream, buf, pre, pim, T);
  hipLaunchKernelGGL(k_iffty, dim3(4096), dim3(256), 0, stream, buf, T);
  hipLaunchKernelGGL(k_back,  dim3(2048), dim3(256), 0, stream, buf, mtxi, T, out);
}